// Round 4
// baseline (709.550 us; speedup 1.0000x reference)
//
#include <hip/hip_runtime.h>
#include <hip/hip_fp16.h>

#define BATCH   64
#define NCAPS   32
#define NROUTES 2048
#define INDIM   16
#define OUTDIM  32

typedef _Float16 f16;
typedef __attribute__((ext_vector_type(8))) _Float16 f16x8;
typedef __attribute__((ext_vector_type(16))) float f32x16;

// ============================================================
// Kernel A: priors[b,c,n,o] = sum_i x[b,n,i] * W[c,n,i,o], fp16 out.
// Split-fp16 MFMA: p = Ah*Bh + Al*Bh + Ah*Bl (fp32 accumulate) ==
// fp32-accurate (lo*lo term ~2^-22 rel, negligible).
// One wave per 8 (c,n) pairs; W read exactly once from HBM.
// MFMA 32x32x16: A[m=lane&31][k=(lane>>5)*8+j], B[k][n=lane&31],
// C: col=lane&31, row=(reg&3)+8*(reg>>2)+4*(lane>>5).
// Orientation: m = batch row, n = o column -> stores hit full 64B lines.
// ============================================================
__global__ __launch_bounds__(256, 4) void caps_priors(
    const float* __restrict__ x,
    const float* __restrict__ W,
    f16* __restrict__ pri)   // [B][C][N][O]
{
    const int bid  = blockIdx.x;          // 2048 blocks
    const int c    = bid >> 6;
    const int tile = bid & 63;
    const int t    = threadIdx.x;
    const int wv   = t >> 6;
    const int l    = t & 63;
    const int lo31 = l & 31;
    const int h    = l >> 5;

    const size_t strideB = (size_t)NCAPS * NROUTES * OUTDIM;  // per-batch stride

    for (int nn = 0; nn < 8; ++nn) {
        const int n = tile * 32 + wv * 8 + nn;

        // ---- B fragment: W[c][n][i = h*8+j][o = lo31] (column reads,
        //      2 x 128B coalesced segments per instruction) ----
        const float* wb = W + (((size_t)c * NROUTES + n) * INDIM + h * 8) * OUTDIM + lo31;
        f16x8 Bh, Bl;
        #pragma unroll
        for (int j = 0; j < 8; ++j) {
            float v = wb[j * OUTDIM];
            f16 hi = (f16)v;
            Bh[j] = hi;
            Bl[j] = (f16)(v - (float)hi);
        }

        // ---- A fragments: x[b][n][i = h*8+j]; A1: b = lo31, A2: b = lo31+32 ----
        const float* xa = x + ((size_t)lo31 * NROUTES + n) * INDIM + h * 8;
        const float* xb = xa + (size_t)32 * NROUTES * INDIM;
        float4 a0 = *(const float4*)xa;
        float4 a1 = *(const float4*)(xa + 4);
        float4 b0 = *(const float4*)xb;
        float4 b1 = *(const float4*)(xb + 4);
        float af[8] = {a0.x,a0.y,a0.z,a0.w,a1.x,a1.y,a1.z,a1.w};
        float bf[8] = {b0.x,b0.y,b0.z,b0.w,b1.x,b1.y,b1.z,b1.w};
        f16x8 A1h, A1l, A2h, A2l;
        #pragma unroll
        for (int j = 0; j < 8; ++j) {
            f16 h1 = (f16)af[j];
            A1h[j] = h1; A1l[j] = (f16)(af[j] - (float)h1);
            f16 h2 = (f16)bf[j];
            A2h[j] = h2; A2l[j] = (f16)(bf[j] - (float)h2);
        }

        f32x16 acc1 = {};
        acc1 = __builtin_amdgcn_mfma_f32_32x32x16_f16(A1h, Bh, acc1, 0, 0, 0);
        acc1 = __builtin_amdgcn_mfma_f32_32x32x16_f16(A1l, Bh, acc1, 0, 0, 0);
        acc1 = __builtin_amdgcn_mfma_f32_32x32x16_f16(A1h, Bl, acc1, 0, 0, 0);
        f32x16 acc2 = {};
        acc2 = __builtin_amdgcn_mfma_f32_32x32x16_f16(A2h, Bh, acc2, 0, 0, 0);
        acc2 = __builtin_amdgcn_mfma_f32_32x32x16_f16(A2l, Bh, acc2, 0, 0, 0);
        acc2 = __builtin_amdgcn_mfma_f32_32x32x16_f16(A2h, Bl, acc2, 0, 0, 0);

        // ---- store: b-row in-lane, o cross-lane -> 2 full 64B lines / instr ----
        f16* pb = pri + ((size_t)c * NROUTES + n) * OUTDIM + lo31;
        #pragma unroll
        for (int r = 0; r < 16; ++r) {
            int brow = (r & 3) + 8 * (r >> 2) + 4 * h;
            pb[(size_t)brow * strideB]        = (f16)acc1[r];
            pb[(size_t)(brow + 32) * strideB] = (f16)acc2[r];
        }
    }
}

// ============================================================
// Kernel B: routing. One block (1024 thr, 16 waves) per (b,c).
// Priors stay PACKED half2 in 32 VGPRs (unpacked on the fly);
// transpose-reduce chunked 4x8 (peak 8 regs); out read from LDS.
// Goal: no scratch spills under the 128-VGPR/1024-thread cap.
// ============================================================
__global__ __launch_bounds__(1024) void caps_route(
    const unsigned short* __restrict__ pri,
    float* __restrict__ out)
{
    const int bid = blockIdx.x;
    const int b = bid >> 5;
    const int c = bid & 31;
    const int t = threadIdx.x;
    const int w = t >> 6;
    const int l = t & 63;

    __shared__ float wmax[16];
    __shared__ float wsum[16];
    __shared__ float swave[16][32];
    __shared__ float outArr[32];

    const int n0 = w * 128 + 2 * l;
    const uint4* pp = (const uint4*)(pri + (((size_t)b * NCAPS + c) * NROUTES + n0) * OUTDIM);
    uint4 q[8];
    #pragma unroll
    for (int k = 0; k < 8; ++k) q[k] = pp[k];
    const unsigned* qu = (const unsigned*)q;   // [0..15] node0, [16..31] node1

    float B0 = 0.f, B1 = 0.f;

    for (int it = 0; it < 3; ++it) {
        // per-wave softmax pieces (global rescale at combine)
        float m = fmaxf(B0, B1);
        #pragma unroll
        for (int mk = 1; mk < 64; mk <<= 1) m = fmaxf(m, __shfl_xor(m, mk, 64));
        float e0 = __expf(B0 - m);
        float e1 = __expf(B1 - m);
        float sm = e0 + e1;
        #pragma unroll
        for (int mk = 1; mk < 64; mk <<= 1) sm += __shfl_xor(sm, mk, 64);
        if (l == 0) { wmax[w] = m; wsum[w] = sm; }

        // s[o] partials, reduced cross-lane in 4 chunks of 8 o's
        #pragma unroll
        for (int ch = 0; ch < 4; ++ch) {
            float s[8];
            #pragma unroll
            for (int k = 0; k < 4; ++k) {
                unsigned u0 = qu[ch * 4 + k];
                unsigned u1 = qu[16 + ch * 4 + k];
                float2 f0 = __half22float2(*(const __half2*)&u0);
                float2 f1 = __half22float2(*(const __half2*)&u1);
                s[2*k]   = e0 * f0.x + e1 * f1.x;
                s[2*k+1] = e0 * f0.y + e1 * f1.y;
            }
            #pragma unroll
            for (int step = 0; step < 3; ++step) {
                const int mk = 1 << step;
                const int half = 4 >> step;
                bool bit = (l & mk) != 0;
                #pragma unroll
                for (int k = 0; k < half; ++k) {
                    float keep = bit ? s[k + half] : s[k];
                    float send = bit ? s[k] : s[k + half];
                    s[k] = keep + __shfl_xor(send, mk, 64);
                }
            }
            float v = s[0];
            v += __shfl_xor(v, 8, 64);
            v += __shfl_xor(v, 16, 64);
            v += __shfl_xor(v, 32, 64);
            if (l < 8) swave[w][ch * 8 + (__brev(l) >> 29)] = v;
        }
        __syncthreads();

        if (t < 32) {
            float M = wmax[0];
            #pragma unroll
            for (int k = 1; k < 16; ++k) M = fmaxf(M, wmax[k]);
            float S = 0.f, sv = 0.f;
            #pragma unroll
            for (int k = 0; k < 16; ++k) {
                float sc = __expf(wmax[k] - M);
                S  += wsum[k] * sc;
                sv += swave[k][t] * sc;
            }
            sv /= S;
            float sq = sv * sv;
            sq += __shfl_xor(sq, 1, 64);
            sq += __shfl_xor(sq, 2, 64);
            sq += __shfl_xor(sq, 4, 64);
            sq += __shfl_xor(sq, 8, 64);
            sq += __shfl_xor(sq, 16, 64);
            float scale = sq / ((1.f + sq) * sqrtf(sq));
            float ov = sv * scale;
            if (it == 2) out[((size_t)b * NCAPS + c) * OUTDIM + t] = ov;
            else         outArr[t] = ov;
        }

        if (it < 2) {
            __syncthreads();
            float d0 = 0.f, d1 = 0.f;
            #pragma unroll
            for (int k = 0; k < 8; ++k) {
                float4 ov = ((const float4*)outArr)[k];   // LDS broadcast
                unsigned u0a = qu[2*k],    u0b = qu[2*k+1];
                unsigned u1a = qu[16+2*k], u1b = qu[16+2*k+1];
                float2 f0a = __half22float2(*(const __half2*)&u0a);
                float2 f0b = __half22float2(*(const __half2*)&u0b);
                float2 f1a = __half22float2(*(const __half2*)&u1a);
                float2 f1b = __half22float2(*(const __half2*)&u1b);
                d0 += f0a.x*ov.x + f0a.y*ov.y + f0b.x*ov.z + f0b.y*ov.w;
                d1 += f1a.x*ov.x + f1a.y*ov.y + f1b.x*ov.z + f1b.y*ov.w;
            }
            B0 += d0; B1 += d1;
        }
    }
}

// ============================================================
// Fallback (round-1 fused kernel, fp32) if ws is too small.
// ============================================================
__global__ __launch_bounds__(1024, 4) void caps_fused(
    const float* __restrict__ x,
    const float* __restrict__ W,
    float* __restrict__ out)
{
    int blk  = blockIdx.x;
    int xcd  = blk & 7;
    int rest = blk >> 3;
    int c = xcd * 4 + (rest >> 6);
    int b = rest & 63;

    int t   = threadIdx.x;
    int w   = t >> 6;
    int l   = t & 63;
    int o   = l & 31;
    int sub = l >> 5;

    __shared__ float Bsh[NROUTES];
    __shared__ float Psh[NROUTES];
    __shared__ float red[1024];
    __shared__ float spart[16][32];
    __shared__ float outArr[32];

    Bsh[t] = 0.0f;
    Bsh[t + 1024] = 0.0f;

    float p[64];
    const int nodeBase = w * 128 + sub;
    const float* Wc = W + (size_t)c * NROUTES * (INDIM * OUTDIM);
    const float* xb = x + (size_t)b * NROUTES * INDIM;

    #pragma unroll 2
    for (int j = 0; j < 64; ++j) {
        int n = nodeBase + 2 * j;
        const float*  wp = Wc + (size_t)n * (INDIM * OUTDIM) + o;
        const float4* xp = (const float4*)(xb + n * INDIM);
        float4 x0 = xp[0], x1 = xp[1], x2 = xp[2], x3 = xp[3];
        float acc = 0.0f;
        acc += x0.x * wp[ 0*32]; acc += x0.y * wp[ 1*32];
        acc += x0.z * wp[ 2*32]; acc += x0.w * wp[ 3*32];
        acc += x1.x * wp[ 4*32]; acc += x1.y * wp[ 5*32];
        acc += x1.z * wp[ 6*32]; acc += x1.w * wp[ 7*32];
        acc += x2.x * wp[ 8*32]; acc += x2.y * wp[ 9*32];
        acc += x2.z * wp[10*32]; acc += x2.w * wp[11*32];
        acc += x3.x * wp[12*32]; acc += x3.y * wp[13*32];
        acc += x3.z * wp[14*32]; acc += x3.w * wp[15*32];
        p[j] = acc;
    }
    __syncthreads();

    for (int it = 0; it < 3; ++it) {
        float m = fmaxf(Bsh[t], Bsh[t + 1024]);
        red[t] = m;
        __syncthreads();
        for (int s = 512; s >= 1; s >>= 1) {
            if (t < s) red[t] = fmaxf(red[t], red[t + s]);
            __syncthreads();
        }
        float M = red[0];
        __syncthreads();

        float e0 = __expf(Bsh[t] - M);
        float e1 = __expf(Bsh[t + 1024] - M);
        Psh[t] = e0;
        Psh[t + 1024] = e1;
        red[t] = e0 + e1;
        __syncthreads();
        for (int s = 512; s >= 1; s >>= 1) {
            if (t < s) red[t] += red[t + s];
            __syncthreads();
        }
        float invS = 1.0f / red[0];
        __syncthreads();

        float local = 0.0f;
        #pragma unroll 8
        for (int j = 0; j < 64; ++j) local += Psh[nodeBase + 2 * j] * p[j];
        local *= invS;
        local += __shfl_xor(local, 32, 64);
        if (l < 32) spart[w][l] = local;
        __syncthreads();

        if (t < 32) {
            float s = 0.0f;
            #pragma unroll
            for (int ww = 0; ww < 16; ++ww) s += spart[ww][t];
            float sq = s * s;
            sq += __shfl_xor(sq, 1, 64);
            sq += __shfl_xor(sq, 2, 64);
            sq += __shfl_xor(sq, 4, 64);
            sq += __shfl_xor(sq, 8, 64);
            sq += __shfl_xor(sq, 16, 64);
            float scale = sq / ((1.0f + sq) * sqrtf(sq));
            outArr[t] = s * scale;
        }
        __syncthreads();

        float outReg = outArr[o];
        if (it < 2) {
            #pragma unroll 8
            for (int j = 0; j < 64; ++j) {
                float a = p[j] * outReg;
                a += __shfl_xor(a, 1, 64);
                a += __shfl_xor(a, 2, 64);
                a += __shfl_xor(a, 4, 64);
                a += __shfl_xor(a, 8, 64);
                a += __shfl_xor(a, 16, 64);
                if ((l & 31) == 0) Bsh[nodeBase + 2 * j] += a;
            }
            __syncthreads();
        }
    }

    if (t < 32) out[((size_t)b * NCAPS + c) * OUTDIM + t] = outArr[t];
}

extern "C" void kernel_launch(void* const* d_in, const int* in_sizes, int n_in,
                              void* d_out, int out_size, void* d_ws, size_t ws_size,
                              hipStream_t stream) {
    const float* x = (const float*)d_in[0];
    const float* W = (const float*)d_in[1];
    float* out = (float*)d_out;

    const size_t need = (size_t)BATCH * NCAPS * NROUTES * OUTDIM * 2;  // 256 MiB fp16
    if (ws_size >= need) {
        caps_priors<<<dim3(2048), dim3(256), 0, stream>>>(x, W, (f16*)d_ws);
        caps_route<<<dim3(BATCH * NCAPS), dim3(1024), 0, stream>>>((const unsigned short*)d_ws, out);
    } else {
        caps_fused<<<dim3(BATCH * NCAPS), dim3(1024), 0, stream>>>(x, W, out);
    }
}